// Round 9
// baseline (521.481 us; speedup 1.0000x reference)
//
#include <hip/hip_runtime.h>
#include <hip/hip_fp16.h>
#include <cstddef>

#define NN 100000
#define NE 800000
#define DIN 128
#define HID 96
#define DOUT 32
static constexpr float BN_EPS = 1e-5f;
#define SCAN_NB ((NN + 255) / 256)   // 391

typedef unsigned short u16;
typedef unsigned int u32;

using f32x4 = __attribute__((ext_vector_type(4))) float;
using bf16x8 = __attribute__((ext_vector_type(8))) short;
using u32x4 = __attribute__((ext_vector_type(4))) unsigned int;

__device__ __forceinline__ float b2f(u32 lo16) {
    union { u32 u; float f; } c; c.u = lo16 << 16; return c.f;
}
__device__ __forceinline__ u16 f2b(float f) {
    union { float f; u32 u; } c; c.f = f;
    return (u16)((c.u + 0x7FFFu + ((c.u >> 16) & 1u)) >> 16);
}
// packed edge: bits[31:15] = src (17b), bits[14:0] = fp16 weight (sign bit 0, w>0)
__device__ __forceinline__ u32 pack_edge(int s, float w) {
    __half h = __float2half(w);
    return ((u32)s << 15) | (u32)__half_as_ushort(h);
}
__device__ __forceinline__ int edge_src(u32 pk) { return (int)(pk >> 15); }
__device__ __forceinline__ float edge_wt(u32 pk) {
    return __half2float(__ushort_as_half((u16)(pk & 0x7FFFu)));
}
// non-temporal 16B load (nt: no L2 allocate) for single-use gathered rows.
// NOTE: __builtin_nontemporal_load requires ext_vector_type, not HIP uint4.
__device__ __forceinline__ u32x4 ldnt4(const void* p) {
    return __builtin_nontemporal_load((const u32x4*)p);
}

// ---------------------------------------------------------------- setup kernels

// Pack W1/W2/W3 into MFMA B-fragment order, bf16 hi/lo split.
// Fragment f = kt*CFT + c; within: lane holds B[k = kt*32 + (lane>>4)*8 + j][col = c*16 + (lane&15)],
// flat u16 index f*512 + lane*8 + j. Lo plane at +nfrag*512.
__global__ __launch_bounds__(256) void k_wpack(const float* __restrict__ W1,
                                               const float* __restrict__ W2,
                                               const float* __restrict__ W3,
                                               u16* __restrict__ w1p,
                                               u16* __restrict__ w2p,
                                               u16* __restrict__ w3p) {
    int e = blockIdx.x * 256 + threadIdx.x;   // < 24576
    const float* W; u16* P; int N, nf, idx;
    if (e < 12288)      { W = W1; P = w1p; N = 96; nf = 24; idx = e; }
    else if (e < 21504) { W = W2; P = w2p; N = 96; nf = 18; idx = e - 12288; }
    else                { W = W3; P = w3p; N = 32; nf = 6;  idx = e - 21504; }
    int f = idx >> 9, r = idx & 511;
    int lane = r >> 3, j = r & 7;
    int CFT = N / 16;
    int kt = f / CFT, c = f % CFT;
    int k = kt * 32 + (lane >> 4) * 8 + j;
    int col = c * 16 + (lane & 15);
    float v = W[k * N + col];
    u16 hi = f2b(v);
    u16 lo = f2b(v - b2f(hi));
    P[idx] = hi;
    P[nf * 512 + idx] = lo;
}

// scan phase 1 + dinv fused
__global__ __launch_bounds__(256) void k_scan1(const int* __restrict__ deg,
                                               int* __restrict__ row_start,
                                               int* __restrict__ blksum,
                                               float* __restrict__ dinv) {
    __shared__ int lds[256];
    int t = threadIdx.x;
    int i = blockIdx.x * 256 + t;
    int v = (i < NN) ? deg[i] : 0;
    if (i < NN) dinv[i] = rsqrtf((float)(v + 1));  // +1 self-loop
    lds[t] = v;
    __syncthreads();
#pragma unroll
    for (int off = 1; off < 256; off <<= 1) {
        int add = (t >= off) ? lds[t - off] : 0;
        __syncthreads();
        lds[t] += add;
        __syncthreads();
    }
    if (i < NN) row_start[i] = lds[t] - v;  // exclusive
    if (t == 255) blksum[blockIdx.x] = lds[255];
}

// scans block sums; also zeroes BN-stat accumulators + finalize counters
__global__ __launch_bounds__(512) void k_scan2(int* __restrict__ blksum,
                                               int* __restrict__ row_start,
                                               float* __restrict__ meta) {
    __shared__ int lds[512];
    int t = threadIdx.x;
    if (t < 384) meta[t] = 0.f;
    if (t < 2) ((int*)meta)[768 + t] = 0;   // agg96 finalize tickets
    int v = (t < SCAN_NB) ? blksum[t] : 0;
    lds[t] = v;
    __syncthreads();
#pragma unroll
    for (int off = 1; off < 512; off <<= 1) {
        int add = (t >= off) ? lds[t - off] : 0;
        __syncthreads();
        lds[t] += add;
        __syncthreads();
    }
    if (t < SCAN_NB) blksum[t] = lds[t] - v;  // exclusive block offset
    if (t == 511) row_start[NN] = lds[511];   // grand total (= NE)
}

__global__ __launch_bounds__(256) void k_scan3(int* __restrict__ row_start,
                                               const int* __restrict__ blksum) {
    int i = blockIdx.x * 256 + threadIdx.x;
    if (i < NN) row_start[i] += blksum[blockIdx.x];
}

// atomic-free scatter: position = row_start[dst] + rank; 4 B packed payload
__global__ void k_scatter(const int* __restrict__ src, const int* __restrict__ dst,
                          const int* __restrict__ row_start,
                          const int* __restrict__ rank,
                          const float* __restrict__ dinv,
                          u32* __restrict__ ewt) {
    int e = blockIdx.x * blockDim.x + threadIdx.x;
    if (e < NE) {
        int d = dst[e];
        int p = row_start[d] + rank[e];
        int s = src[e];
        ewt[p] = pack_edge(s, dinv[s]);
    }
}

// ---------------------------------------------------------------- GEMM (bf16 MFMA, hi/lo split)
// Z[M x N](bf16) = f(X)[M x K] @ W[K x N], f = optional relu(a*x+c) per K-channel.
// 3-pass bf16 split (Ah*Bh + Al*Bh + Ah*Bl) keeps ~fp32 precision.
// Block = 64 rows x N cols; full-K A tile staged in LDS once (hi/lo), single barrier.
// B fragments come pre-packed from global (k_wpack), L2-hot, no LDS.
template <int K, int N, bool FUSE, typename XT>
__device__ __forceinline__ void gemmM_body(int bid, const XT* __restrict__ X,
                                           const u16* __restrict__ Wp,
                                           u16* __restrict__ Z,
                                           const float* __restrict__ bnA,
                                           const float* __restrict__ bnC, int M) {
    constexpr int KT = K / 32;          // 4 or 3
    constexpr int CFT = N / 16;         // 6 or 2
    constexpr int WN = (N == 96) ? 2 : 1;
    constexpr int WM = 4 / WN;          // 2 or 4
    constexpr int CF = CFT / WN;        // 3 or 2
    constexpr int RF = 64 / (WM * 16);  // 2 or 1
    constexpr int XSB = K + 8;          // LDS row stride (bf16), 16B-aligned
    __shared__ u16 Ah[64 * XSB];
    __shared__ u16 Al[64 * XSB];
    __shared__ float As[FUSE ? K : 1], Cs[FUSE ? K : 1];

    int tid = threadIdx.x;
    if (FUSE) {
        if (tid < K) { As[tid] = bnA[tid]; Cs[tid] = bnC[tid]; }
        __syncthreads();
    }
    int row0 = bid * 64;
    int sr = tid >> 2, sq = tid & 3;
    int grow = row0 + sr;
    if constexpr (sizeof(XT) == 4) {
        // fp32 X, K=128: 8 float4/thread, cols sq*32 + i*4
#pragma unroll
        for (int i = 0; i < 8; ++i) {
            int c0 = sq * 32 + i * 4;
            float4 v = make_float4(0.f, 0.f, 0.f, 0.f);
            if (grow < M) v = *(const float4*)&X[(size_t)grow * K + c0];
            float vv[4] = {v.x, v.y, v.z, v.w};
            u32 hpk[2], lpk[2];
#pragma unroll
            for (int p = 0; p < 2; ++p) {
                u16 h0 = f2b(vv[2 * p]), h1 = f2b(vv[2 * p + 1]);
                u16 l0 = f2b(vv[2 * p] - b2f(h0));
                u16 l1 = f2b(vv[2 * p + 1] - b2f(h1));
                hpk[p] = (u32)h0 | ((u32)h1 << 16);
                lpk[p] = (u32)l0 | ((u32)l1 << 16);
            }
            *(uint2*)&Ah[sr * XSB + c0] = make_uint2(hpk[0], hpk[1]);
            *(uint2*)&Al[sr * XSB + c0] = make_uint2(lpk[0], lpk[1]);
        }
    } else {
        // bf16 X, K=96: 3 uint4/thread, cols sq*24 + i*8; BN+ReLU fused in fp32
#pragma unroll
        for (int i = 0; i < 3; ++i) {
            int c0 = sq * 24 + i * 8;
            uint4 v = make_uint4(0, 0, 0, 0);
            if (grow < M) v = *(const uint4*)&X[(size_t)grow * K + c0];
            u32 w[4] = {v.x, v.y, v.z, v.w};
            u32 hq[4], lq[4];
#pragma unroll
            for (int p = 0; p < 4; ++p) {
                float x0 = b2f(w[p] & 0xFFFFu);
                float x1 = b2f(w[p] >> 16);
                if (FUSE) {
                    x0 = fmaxf(fmaf(As[c0 + 2 * p], x0, Cs[c0 + 2 * p]), 0.f);
                    x1 = fmaxf(fmaf(As[c0 + 2 * p + 1], x1, Cs[c0 + 2 * p + 1]), 0.f);
                }
                u16 h0 = f2b(x0), h1 = f2b(x1);
                u16 l0 = f2b(x0 - b2f(h0)), l1 = f2b(x1 - b2f(h1));
                hq[p] = (u32)h0 | ((u32)h1 << 16);
                lq[p] = (u32)l0 | ((u32)l1 << 16);
            }
            *(uint4*)&Ah[sr * XSB + c0] = make_uint4(hq[0], hq[1], hq[2], hq[3]);
            *(uint4*)&Al[sr * XSB + c0] = make_uint4(lq[0], lq[1], lq[2], lq[3]);
        }
    }
    __syncthreads();

    int wid = tid >> 6, lane = tid & 63;
    int wm = wid & (WM - 1), wn = wid / WM;
    int lr = lane & 15, lg = lane >> 4;
    f32x4 acc[RF][CF];
#pragma unroll
    for (int a = 0; a < RF; ++a)
#pragma unroll
        for (int b = 0; b < CF; ++b) acc[a][b] = (f32x4){0.f, 0.f, 0.f, 0.f};

    const u16* WpLo = Wp + KT * CFT * 512;
#pragma unroll
    for (int kt = 0; kt < KT; ++kt) {
        bf16x8 ah[RF], al[RF];
#pragma unroll
        for (int rf = 0; rf < RF; ++rf) {
            int row = wm * (RF * 16) + rf * 16 + lr;
            ah[rf] = *(const bf16x8*)&Ah[row * XSB + kt * 32 + lg * 8];
            al[rf] = *(const bf16x8*)&Al[row * XSB + kt * 32 + lg * 8];
        }
#pragma unroll
        for (int cf = 0; cf < CF; ++cf) {
            int f = kt * CFT + wn * CF + cf;
            bf16x8 bh = *(const bf16x8*)&Wp[f * 512 + lane * 8];
            bf16x8 bl = *(const bf16x8*)&WpLo[f * 512 + lane * 8];
#pragma unroll
            for (int rf = 0; rf < RF; ++rf) {
                acc[rf][cf] = __builtin_amdgcn_mfma_f32_16x16x32_bf16(ah[rf], bh, acc[rf][cf], 0, 0, 0);
                acc[rf][cf] = __builtin_amdgcn_mfma_f32_16x16x32_bf16(al[rf], bh, acc[rf][cf], 0, 0, 0);
                acc[rf][cf] = __builtin_amdgcn_mfma_f32_16x16x32_bf16(ah[rf], bl, acc[rf][cf], 0, 0, 0);
            }
        }
    }
#pragma unroll
    for (int rf = 0; rf < RF; ++rf)
#pragma unroll
        for (int cf = 0; cf < CF; ++cf)
#pragma unroll
            for (int rr = 0; rr < 4; ++rr) {
                int gr = row0 + wm * (RF * 16) + rf * 16 + lg * 4 + rr;
                if (gr < M) {
                    int col = (wn * CF + cf) * 16 + lr;
                    Z[(size_t)gr * N + col] = f2b(acc[rf][cf][rr]);
                }
            }
}

template <int K, int N, bool FUSE, typename XT>
__global__ __launch_bounds__(256) void k_gemm(const XT* __restrict__ X,
                                              const u16* __restrict__ Wp,
                                              u16* __restrict__ Z,
                                              const float* __restrict__ bnA,
                                              const float* __restrict__ bnC, int M) {
    gemmM_body<K, N, FUSE, XT>(blockIdx.x, X, Wp, Z, bnA, bnC, M);
}

// fused: blocks [0, gemm_blocks) do GEMM1; the rest do the edge histogram
__global__ __launch_bounds__(256) void k_gemm1_hist(const float* __restrict__ X,
                                                    const u16* __restrict__ Wp,
                                                    u16* __restrict__ Z, int M,
                                                    int gemm_blocks,
                                                    const int* __restrict__ dst,
                                                    int* __restrict__ deg,
                                                    int* __restrict__ rank) {
    if ((int)blockIdx.x < gemm_blocks) {
        gemmM_body<DIN, HID, false, float>(blockIdx.x, X, Wp, Z, nullptr, nullptr, M);
    } else {
        int e = ((int)blockIdx.x - gemm_blocks) * 256 + (int)threadIdx.x;
        if (e < NE) rank[e] = atomicAdd(&deg[dst[e]], 1);
    }
}

// ---------------------------------------------------------------- aggregation, 96ch (bf16)
// One wave per node. dwordx4 gather geometry: row = 192 B = 12 lanes x 16 B.
//   lane = (r, j): r = lane>>4 in [0,4) = edge slot, j = lane&15 (j>=12 dup j=11).
//   One gather instruction fetches FOUR edge rows.
// Row gathers use NON-TEMPORAL loads (no L2 allocate): rows are single-use per
// wave; the hypothesis under test is that streaming from L3 beats the ~1
// line-fill/cycle/XCD L2-allocate path even at +58% request count.
// Epilogue: BN coefficient finalize fused via last-block ticket (replaces k_bncoef).
#define ACC8(UB, W)                                                     \
    acc[0] = fmaf(W, b2f((UB).x & 0xFFFFu), acc[0]);                    \
    acc[1] = fmaf(W, b2f((UB).x >> 16), acc[1]);                        \
    acc[2] = fmaf(W, b2f((UB).y & 0xFFFFu), acc[2]);                    \
    acc[3] = fmaf(W, b2f((UB).y >> 16), acc[3]);                        \
    acc[4] = fmaf(W, b2f((UB).z & 0xFFFFu), acc[4]);                    \
    acc[5] = fmaf(W, b2f((UB).z >> 16), acc[5]);                        \
    acc[6] = fmaf(W, b2f((UB).w & 0xFFFFu), acc[6]);                    \
    acc[7] = fmaf(W, b2f((UB).w >> 16), acc[7]);

__global__ __launch_bounds__(256) void k_agg96(const u16* __restrict__ Z,
                                               u16* __restrict__ H,
                                               const float* __restrict__ bias,
                                               const int* __restrict__ row_start,
                                               const u32* __restrict__ ewt,
                                               const float* __restrict__ dinv,
                                               float* __restrict__ gsum,
                                               float* __restrict__ gsq,
                                               const float* __restrict__ g,
                                               const float* __restrict__ be,
                                               float* __restrict__ bnA,
                                               float* __restrict__ bnC,
                                               int* __restrict__ cnt) {
    __shared__ float ssum[96], ssq[96];
    int tid = threadIdx.x;
    if (tid < 96) { ssum[tid] = 0.f; ssq[tid] = 0.f; }
    __syncthreads();
    int wid = tid >> 6, lane = tid & 63;
    int r = lane >> 4;                   // edge slot 0..3
    int jraw = lane & 15;
    int j = jraw < 12 ? jraw : 11;       // 16B slot within the 192B row
    bool jact = jraw < 12;
    u32 j16 = (u32)j << 4;
    const char* zb = (const char*)Z;     // row stride 192 B
    float bia[8];
#pragma unroll
    for (int k = 0; k < 8; ++k) bia[k] = bias[8 * j + k];
    float lsum[8], lsq[8];
#pragma unroll
    for (int k = 0; k < 8; ++k) { lsum[k] = 0.f; lsq[k] = 0.f; }
    const int S = gridDim.x * 4;

    int n = blockIdx.x * 4 + wid;
    int e0 = 0, e1 = 0;
    u32 pr = 0;
    if (n < NN) {
        e0 = row_start[n]; e1 = row_start[n + 1];
        if (e0 + lane < e1) pr = ewt[e0 + lane];
    }
    while (n < NN) {
        int n2 = n + S;
        int e0n = 0, e1n = 0;
        if (n2 < NN) { e0n = row_start[n2]; e1n = row_start[n2 + 1]; }
        u32 prn = 0;
        if (n2 < NN && e0n + lane < e1n) prn = ewt[e0n + lane];

        float dn = dinv[n];
        int m = e1 - e0;
        float acc[8];
        if (r == 0) {
            u32x4 us4 = ldnt4(zb + (u32)n * 192u + j16);
            acc[0] = dn * b2f(us4.x & 0xFFFFu); acc[1] = dn * b2f(us4.x >> 16);
            acc[2] = dn * b2f(us4.y & 0xFFFFu); acc[3] = dn * b2f(us4.y >> 16);
            acc[4] = dn * b2f(us4.z & 0xFFFFu); acc[5] = dn * b2f(us4.z >> 16);
            acc[6] = dn * b2f(us4.w & 0xFFFFu); acc[7] = dn * b2f(us4.w >> 16);
        } else {
#pragma unroll
            for (int k = 0; k < 8; ++k) acc[k] = 0.f;
        }

        if (m <= 16) {
            u32x4 ub[4]; float wc[4];
            int nch = (m + 3) >> 2;
#pragma unroll
            for (int c = 0; c < 4; ++c) {
                if (c < nch) {
                    int e = 4 * c + r;
                    u32 pk = __shfl(pr, e < m ? e : 0);
                    wc[c] = (e < m) ? edge_wt(pk) : 0.f;
                    ub[c] = ldnt4(zb + (pk >> 15) * 192u + j16);
                }
            }
#pragma unroll
            for (int c = 0; c < 4; ++c) {
                if (c < nch) { ACC8(ub[c], wc[c]); }
            }
        } else {
            // rare: deg > 16; windows of 64 edges, 4-edge chunks (latency exposed)
            for (int base = 0; base < m; base += 64) {
                u32 cw = pr;
                if (base) {
                    int idx = e0 + base + lane;
                    cw = (idx < e1) ? ewt[idx] : 0;
                }
                int lim = m - base; if (lim > 64) lim = 64;
                for (int c = 0; c < lim; c += 4) {
                    int e = c + r;
                    u32 pk = __shfl(cw, e < lim ? e : 0);
                    float w = (e < lim) ? edge_wt(pk) : 0.f;
                    u32x4 ub = ldnt4(zb + (pk >> 15) * 192u + j16);
                    ACC8(ub, w);
                }
            }
        }

        // combine across edge slots: lanes {l, l^16, l^32, l^48} share channels
#pragma unroll
        for (int k = 0; k < 8; ++k) {
            float v = acc[k];
            v += __shfl_xor(v, 16);
            v += __shfl_xor(v, 32);
            acc[k] = v;
        }
        if (r == 0 && jact) {
            float h[8];
#pragma unroll
            for (int k = 0; k < 8; ++k) {
                h[k] = fmaf(dn, acc[k], bia[k]);
                lsum[k] += h[k];
                lsq[k] = fmaf(h[k], h[k], lsq[k]);
            }
            uint4 o;
            o.x = (u32)f2b(h[0]) | ((u32)f2b(h[1]) << 16);
            o.y = (u32)f2b(h[2]) | ((u32)f2b(h[3]) << 16);
            o.z = (u32)f2b(h[4]) | ((u32)f2b(h[5]) << 16);
            o.w = (u32)f2b(h[6]) | ((u32)f2b(h[7]) << 16);
            *(uint4*)((char*)H + (u32)n * 192u + j16) = o;
        }
        n = n2; e0 = e0n; e1 = e1n; pr = prn;
    }
    if (r == 0 && jact) {
#pragma unroll
        for (int k = 0; k < 8; ++k) {
            atomicAdd(&ssum[8 * j + k], lsum[k]);
            atomicAdd(&ssq[8 * j + k], lsq[k]);
        }
    }
    __syncthreads();
    if (tid < 96) { atomicAdd(&gsum[tid], ssum[tid]); atomicAdd(&gsq[tid], ssq[tid]); }
    __syncthreads();

    // ---- last-block BN-coefficient finalize (replaces k_bncoef launch)
    __shared__ int lastBlk;
    if (tid == 0) {
        __threadfence();
        lastBlk = (atomicAdd(cnt, 1) == (int)gridDim.x - 1);
    }
    __syncthreads();
    if (lastBlk && tid < 96) {
        float s = atomicAdd(&gsum[tid], 0.f);   // coherent read
        float q = atomicAdd(&gsq[tid], 0.f);
        float mean = s * (1.f / NN);
        float var = q * (1.f / NN) - mean * mean;
        float inv = rsqrtf(var + BN_EPS);
        float a = g[tid] * inv;
        bnA[tid] = a;
        bnC[tid] = fmaf(-a, mean, be[tid]);
    }
}

// ---------------------------------------------------------------- final agg + log_softmax
// 4 nodes per wave (16-lane groups). Full-window gather: all <=16 edges in flight.
__global__ __launch_bounds__(256) void k_agg32_lsm(const u16* __restrict__ Z,
                                                   float* __restrict__ Out,
                                                   const float* __restrict__ bias,
                                                   const int* __restrict__ row_start,
                                                   const u32* __restrict__ ewt,
                                                   const float* __restrict__ dinv) {
    int tid = threadIdx.x;
    int wid = tid >> 6, lane = tid & 63;
    int g = lane >> 4, sl = lane & 15;
    const u32* zu = (const u32*)Z;  // row stride 16 dwords
    float b0 = bias[2 * sl], b1 = bias[2 * sl + 1];
    int stride = gridDim.x * 16;
    for (int n0 = (blockIdx.x * 4 + wid) * 4; n0 < NN; n0 += stride) {
        int n = n0 + g;
        bool vn = n < NN;
        float dn = vn ? dinv[n] : 0.f;
        u32 uself = vn ? zu[(size_t)n * 16 + sl] : 0;
        float a0a = dn * b2f(uself & 0xFFFFu);
        float a1a = dn * b2f(uself >> 16);
        float a0b = 0.f, a1b = 0.f;
        int e0 = vn ? row_start[n] : 0, e1 = vn ? row_start[n + 1] : 0;
        for (int eb = e0; eb < e1; eb += 16) {
            int m = e1 - eb; if (m > 16) m = 16;
            int idx = eb + sl;
            u32 plv = (idx < e1) ? ewt[idx] : 0;
            u32 u_[16]; float w_[16];
#pragma unroll
            for (int q = 0; q < 16; ++q) {
                bool v = q < m;
                u32 pk = __shfl(plv, v ? q : 0, 16);
                w_[q] = v ? edge_wt(pk) : 0.f;
                u_[q] = zu[(size_t)edge_src(pk) * 16 + sl];
            }
#pragma unroll
            for (int q = 0; q < 16; q += 2) {
                a0a = fmaf(w_[q], b2f(u_[q] & 0xFFFFu), a0a);
                a1a = fmaf(w_[q], b2f(u_[q] >> 16), a1a);
                a0b = fmaf(w_[q + 1], b2f(u_[q + 1] & 0xFFFFu), a0b);
                a1b = fmaf(w_[q + 1], b2f(u_[q + 1] >> 16), a1b);
            }
        }
        float v0 = fmaf(dn, a0a + a0b, b0);
        float v1 = fmaf(dn, a1a + a1b, b1);
        float mx = fmaxf(v0, v1);
#pragma unroll
        for (int off = 8; off; off >>= 1) mx = fmaxf(mx, __shfl_xor(mx, off, 16));
        float ex = __expf(v0 - mx) + __expf(v1 - mx);
#pragma unroll
        for (int off = 8; off; off >>= 1) ex += __shfl_xor(ex, off, 16);
        float lse = mx + __logf(ex);
        if (vn) {
            float2 o = make_float2(v0 - lse, v1 - lse);
            *(float2*)&Out[(size_t)n * 32 + 2 * sl] = o;
        }
    }
}

// ---------------------------------------------------------------- launch

extern "C" void kernel_launch(void* const* d_in, const int* in_sizes, int n_in,
                              void* d_out, int out_size, void* d_ws, size_t ws_size,
                              hipStream_t stream) {
    const float* x  = (const float*)d_in[0];
    const int* ei   = (const int*)d_in[1];   // [2, NE]: src then dst
    const float* W1 = (const float*)d_in[2];
    const float* b1 = (const float*)d_in[3];
    const float* W2 = (const float*)d_in[4];
    const float* b2 = (const float*)d_in[5];
    const float* W3 = (const float*)d_in[6];
    const float* b3 = (const float*)d_in[7];
    const float* g1 = (const float*)d_in[8];
    const float* be1 = (const float*)d_in[9];
    const float* g2 = (const float*)d_in[10];
    const float* be2 = (const float*)d_in[11];
    float* out = (float*)d_out;

    const int* src = ei;
    const int* dst = ei + NE;

    char* p = (char*)d_ws;
    size_t off = 0;
    auto take = [&](size_t bytes) {
        char* r = p + off;
        off = (off + bytes + 255) & ~(size_t)255;
        return r;
    };
    float* dinv      = (float*)take(NN * 4);
    int*   deg       = (int*)take(NN * 4);
    int*   row_start = (int*)take((NN + 1) * 4);
    int*   blksum    = (int*)take(SCAN_NB * 4);
    int*   rank      = (int*)take((size_t)NE * 4);
    u32*   ewt       = (u32*)take((size_t)NE * 4);
    float* meta      = (float*)take(772 * 4);
    u16*   w1p       = (u16*)take(24 * 512 * 2 * 2);   // hi+lo
    u16*   w2p       = (u16*)take(18 * 512 * 2 * 2);
    u16*   w3p       = (u16*)take(6 * 512 * 2 * 2);
    u16*   bufA      = (u16*)take((size_t)NN * HID * 2);
    u16*   bufB      = (u16*)take((size_t)NN * HID * 2);

    float* sum1 = meta + 0,   *sq1 = meta + 96;
    float* sum2 = meta + 192, *sq2 = meta + 288;
    float* bnA1 = meta + 384, *bnC1 = meta + 480;
    float* bnA2 = meta + 576, *bnC2 = meta + 672;
    int*   cnt1 = (int*)meta + 768;
    int*   cnt2 = (int*)meta + 769;

    const int EB = (NE + 255) / 256;   // 3125
    const int MB = (NN + 63) / 64;     // 1563 GEMM blocks
    const int AB = 2048;               // agg blocks: 8 per CU

    (void)hipMemsetAsync(deg, 0, NN * 4, stream);
    k_wpack<<<96, 256, 0, stream>>>(W1, W2, W3, w1p, w2p, w3p);
    // GEMM1 (independent of graph setup) fused with edge histogram
    k_gemm1_hist<<<MB + EB, 256, 0, stream>>>(x, w1p, bufA, NN, MB, dst, deg, rank);
    k_scan1<<<SCAN_NB, 256, 0, stream>>>(deg, row_start, blksum, dinv);
    k_scan2<<<1, 512, 0, stream>>>(blksum, row_start, meta);
    k_scan3<<<SCAN_NB, 256, 0, stream>>>(row_start, blksum);
    k_scatter<<<EB, 256, 0, stream>>>(src, dst, row_start, rank, dinv, ewt);

    // layer 1 aggregation (z1 already in bufA); BN coefs finalized in-kernel
    k_agg96<<<AB, 256, 0, stream>>>(bufA, bufB, b1, row_start, ewt, dinv,
                                    sum1, sq1, g1, be1, bnA1, bnC1, cnt1);

    // layer 2: z = relu(bn(h1))@W2 ; h2 = agg(z)+b2 (+stats)
    k_gemm<HID, HID, true, u16><<<MB, 256, 0, stream>>>(bufB, w2p, bufA, bnA1, bnC1, NN);
    k_agg96<<<AB, 256, 0, stream>>>(bufA, bufB, b2, row_start, ewt, dinv,
                                    sum2, sq2, g2, be2, bnA2, bnC2, cnt2);

    // layer 3: z = relu(bn(h2))@W3 ; out = log_softmax(agg(z)+b3)
    k_gemm<HID, DOUT, true, u16><<<MB, 256, 0, stream>>>(bufB, w3p, bufA, bnA2, bnC2, NN);
    k_agg32_lsm<<<AB, 256, 0, stream>>>(bufA, out, b3, row_start, ewt, dinv);

    (void)in_sizes; (void)n_in; (void)out_size; (void)ws_size;
}

// Round 10
// 445.651 us; speedup vs baseline: 1.1702x; 1.1702x over previous
//
#include <hip/hip_runtime.h>
#include <hip/hip_fp16.h>
#include <cstddef>

#define NN 100000
#define NE 800000
#define DIN 128
#define HID 96
#define DOUT 32
static constexpr float BN_EPS = 1e-5f;
#define SCAN_NB ((NN + 255) / 256)   // 391

typedef unsigned short u16;
typedef unsigned int u32;

using f32x4 = __attribute__((ext_vector_type(4))) float;
using bf16x8 = __attribute__((ext_vector_type(8))) short;
using u32x4 = __attribute__((ext_vector_type(4))) unsigned int;

__device__ __forceinline__ float b2f(u32 lo16) {
    union { u32 u; float f; } c; c.u = lo16 << 16; return c.f;
}
__device__ __forceinline__ u16 f2b(float f) {
    union { float f; u32 u; } c; c.f = f;
    return (u16)((c.u + 0x7FFFu + ((c.u >> 16) & 1u)) >> 16);
}
// packed edge: bits[31:15] = src (17b), bits[14:0] = fp16 weight (sign bit 0, w>0)
__device__ __forceinline__ u32 pack_edge(int s, float w) {
    __half h = __float2half(w);
    return ((u32)s << 15) | (u32)__half_as_ushort(h);
}
__device__ __forceinline__ int edge_src(u32 pk) { return (int)(pk >> 15); }
__device__ __forceinline__ float edge_wt(u32 pk) {
    return __half2float(__ushort_as_half((u16)(pk & 0x7FFFu)));
}
// 16B gather load. NOTE: round-9 A/B showed non-temporal (no-L2-allocate) here
// is 1.9x SLOWER (84 -> 157 us): L2 hits on Poisson reuse carry ~1/3 of the
// stream. Keep the normal L2-allocating path.
__device__ __forceinline__ u32x4 ld16(const void* p) {
    return *(const u32x4*)p;
}

// ---------------------------------------------------------------- setup kernels

// Pack W1/W2/W3 into MFMA B-fragment order, bf16 hi/lo split.
// Fragment f = kt*CFT + c; within: lane holds B[k = kt*32 + (lane>>4)*8 + j][col = c*16 + (lane&15)],
// flat u16 index f*512 + lane*8 + j. Lo plane at +nfrag*512.
__global__ __launch_bounds__(256) void k_wpack(const float* __restrict__ W1,
                                               const float* __restrict__ W2,
                                               const float* __restrict__ W3,
                                               u16* __restrict__ w1p,
                                               u16* __restrict__ w2p,
                                               u16* __restrict__ w3p) {
    int e = blockIdx.x * 256 + threadIdx.x;   // < 24576
    const float* W; u16* P; int N, nf, idx;
    if (e < 12288)      { W = W1; P = w1p; N = 96; nf = 24; idx = e; }
    else if (e < 21504) { W = W2; P = w2p; N = 96; nf = 18; idx = e - 12288; }
    else                { W = W3; P = w3p; N = 32; nf = 6;  idx = e - 21504; }
    int f = idx >> 9, r = idx & 511;
    int lane = r >> 3, j = r & 7;
    int CFT = N / 16;
    int kt = f / CFT, c = f % CFT;
    int k = kt * 32 + (lane >> 4) * 8 + j;
    int col = c * 16 + (lane & 15);
    float v = W[k * N + col];
    u16 hi = f2b(v);
    u16 lo = f2b(v - b2f(hi));
    P[idx] = hi;
    P[nf * 512 + idx] = lo;
}

// scan phase 1 + dinv fused
__global__ __launch_bounds__(256) void k_scan1(const int* __restrict__ deg,
                                               int* __restrict__ row_start,
                                               int* __restrict__ blksum,
                                               float* __restrict__ dinv) {
    __shared__ int lds[256];
    int t = threadIdx.x;
    int i = blockIdx.x * 256 + t;
    int v = (i < NN) ? deg[i] : 0;
    if (i < NN) dinv[i] = rsqrtf((float)(v + 1));  // +1 self-loop
    lds[t] = v;
    __syncthreads();
#pragma unroll
    for (int off = 1; off < 256; off <<= 1) {
        int add = (t >= off) ? lds[t - off] : 0;
        __syncthreads();
        lds[t] += add;
        __syncthreads();
    }
    if (i < NN) row_start[i] = lds[t] - v;  // exclusive
    if (t == 255) blksum[blockIdx.x] = lds[255];
}

// scans block sums; also zeroes BN-stat accumulators + finalize counters
__global__ __launch_bounds__(512) void k_scan2(int* __restrict__ blksum,
                                               int* __restrict__ row_start,
                                               float* __restrict__ meta) {
    __shared__ int lds[512];
    int t = threadIdx.x;
    if (t < 384) meta[t] = 0.f;
    if (t < 2) ((int*)meta)[768 + t] = 0;   // agg96 finalize tickets
    int v = (t < SCAN_NB) ? blksum[t] : 0;
    lds[t] = v;
    __syncthreads();
#pragma unroll
    for (int off = 1; off < 512; off <<= 1) {
        int add = (t >= off) ? lds[t - off] : 0;
        __syncthreads();
        lds[t] += add;
        __syncthreads();
    }
    if (t < SCAN_NB) blksum[t] = lds[t] - v;  // exclusive block offset
    if (t == 511) row_start[NN] = lds[511];   // grand total (= NE)
}

__global__ __launch_bounds__(256) void k_scan3(int* __restrict__ row_start,
                                               const int* __restrict__ blksum) {
    int i = blockIdx.x * 256 + threadIdx.x;
    if (i < NN) row_start[i] += blksum[blockIdx.x];
}

// atomic-free scatter: position = row_start[dst] + rank; 4 B packed payload
__global__ void k_scatter(const int* __restrict__ src, const int* __restrict__ dst,
                          const int* __restrict__ row_start,
                          const int* __restrict__ rank,
                          const float* __restrict__ dinv,
                          u32* __restrict__ ewt) {
    int e = blockIdx.x * blockDim.x + threadIdx.x;
    if (e < NE) {
        int d = dst[e];
        int p = row_start[d] + rank[e];
        int s = src[e];
        ewt[p] = pack_edge(s, dinv[s]);
    }
}

// ---------------------------------------------------------------- GEMM (bf16 MFMA, hi/lo split)
// Z[M x N](bf16) = f(X)[M x K] @ W[K x N], f = optional relu(a*x+c) per K-channel.
// 3-pass bf16 split (Ah*Bh + Al*Bh + Ah*Bl) keeps ~fp32 precision.
// Block = 64 rows x N cols; full-K A tile staged in LDS once (hi/lo), single barrier.
// B fragments come pre-packed from global (k_wpack), L2-hot, no LDS.
template <int K, int N, bool FUSE, typename XT>
__device__ __forceinline__ void gemmM_body(int bid, const XT* __restrict__ X,
                                           const u16* __restrict__ Wp,
                                           u16* __restrict__ Z,
                                           const float* __restrict__ bnA,
                                           const float* __restrict__ bnC, int M) {
    constexpr int KT = K / 32;          // 4 or 3
    constexpr int CFT = N / 16;         // 6 or 2
    constexpr int WN = (N == 96) ? 2 : 1;
    constexpr int WM = 4 / WN;          // 2 or 4
    constexpr int CF = CFT / WN;        // 3 or 2
    constexpr int RF = 64 / (WM * 16);  // 2 or 1
    constexpr int XSB = K + 8;          // LDS row stride (bf16), 16B-aligned
    __shared__ u16 Ah[64 * XSB];
    __shared__ u16 Al[64 * XSB];
    __shared__ float As[FUSE ? K : 1], Cs[FUSE ? K : 1];

    int tid = threadIdx.x;
    if (FUSE) {
        if (tid < K) { As[tid] = bnA[tid]; Cs[tid] = bnC[tid]; }
        __syncthreads();
    }
    int row0 = bid * 64;
    int sr = tid >> 2, sq = tid & 3;
    int grow = row0 + sr;
    if constexpr (sizeof(XT) == 4) {
        // fp32 X, K=128: 8 float4/thread, cols sq*32 + i*4
#pragma unroll
        for (int i = 0; i < 8; ++i) {
            int c0 = sq * 32 + i * 4;
            float4 v = make_float4(0.f, 0.f, 0.f, 0.f);
            if (grow < M) v = *(const float4*)&X[(size_t)grow * K + c0];
            float vv[4] = {v.x, v.y, v.z, v.w};
            u32 hpk[2], lpk[2];
#pragma unroll
            for (int p = 0; p < 2; ++p) {
                u16 h0 = f2b(vv[2 * p]), h1 = f2b(vv[2 * p + 1]);
                u16 l0 = f2b(vv[2 * p] - b2f(h0));
                u16 l1 = f2b(vv[2 * p + 1] - b2f(h1));
                hpk[p] = (u32)h0 | ((u32)h1 << 16);
                lpk[p] = (u32)l0 | ((u32)l1 << 16);
            }
            *(uint2*)&Ah[sr * XSB + c0] = make_uint2(hpk[0], hpk[1]);
            *(uint2*)&Al[sr * XSB + c0] = make_uint2(lpk[0], lpk[1]);
        }
    } else {
        // bf16 X, K=96: 3 uint4/thread, cols sq*24 + i*8; BN+ReLU fused in fp32
#pragma unroll
        for (int i = 0; i < 3; ++i) {
            int c0 = sq * 24 + i * 8;
            uint4 v = make_uint4(0, 0, 0, 0);
            if (grow < M) v = *(const uint4*)&X[(size_t)grow * K + c0];
            u32 w[4] = {v.x, v.y, v.z, v.w};
            u32 hq[4], lq[4];
#pragma unroll
            for (int p = 0; p < 4; ++p) {
                float x0 = b2f(w[p] & 0xFFFFu);
                float x1 = b2f(w[p] >> 16);
                if (FUSE) {
                    x0 = fmaxf(fmaf(As[c0 + 2 * p], x0, Cs[c0 + 2 * p]), 0.f);
                    x1 = fmaxf(fmaf(As[c0 + 2 * p + 1], x1, Cs[c0 + 2 * p + 1]), 0.f);
                }
                u16 h0 = f2b(x0), h1 = f2b(x1);
                u16 l0 = f2b(x0 - b2f(h0)), l1 = f2b(x1 - b2f(h1));
                hq[p] = (u32)h0 | ((u32)h1 << 16);
                lq[p] = (u32)l0 | ((u32)l1 << 16);
            }
            *(uint4*)&Ah[sr * XSB + c0] = make_uint4(hq[0], hq[1], hq[2], hq[3]);
            *(uint4*)&Al[sr * XSB + c0] = make_uint4(lq[0], lq[1], lq[2], lq[3]);
        }
    }
    __syncthreads();

    int wid = tid >> 6, lane = tid & 63;
    int wm = wid & (WM - 1), wn = wid / WM;
    int lr = lane & 15, lg = lane >> 4;
    f32x4 acc[RF][CF];
#pragma unroll
    for (int a = 0; a < RF; ++a)
#pragma unroll
        for (int b = 0; b < CF; ++b) acc[a][b] = (f32x4){0.f, 0.f, 0.f, 0.f};

    const u16* WpLo = Wp + KT * CFT * 512;
#pragma unroll
    for (int kt = 0; kt < KT; ++kt) {
        bf16x8 ah[RF], al[RF];
#pragma unroll
        for (int rf = 0; rf < RF; ++rf) {
            int row = wm * (RF * 16) + rf * 16 + lr;
            ah[rf] = *(const bf16x8*)&Ah[row * XSB + kt * 32 + lg * 8];
            al[rf] = *(const bf16x8*)&Al[row * XSB + kt * 32 + lg * 8];
        }
#pragma unroll
        for (int cf = 0; cf < CF; ++cf) {
            int f = kt * CFT + wn * CF + cf;
            bf16x8 bh = *(const bf16x8*)&Wp[f * 512 + lane * 8];
            bf16x8 bl = *(const bf16x8*)&WpLo[f * 512 + lane * 8];
#pragma unroll
            for (int rf = 0; rf < RF; ++rf) {
                acc[rf][cf] = __builtin_amdgcn_mfma_f32_16x16x32_bf16(ah[rf], bh, acc[rf][cf], 0, 0, 0);
                acc[rf][cf] = __builtin_amdgcn_mfma_f32_16x16x32_bf16(al[rf], bh, acc[rf][cf], 0, 0, 0);
                acc[rf][cf] = __builtin_amdgcn_mfma_f32_16x16x32_bf16(ah[rf], bl, acc[rf][cf], 0, 0, 0);
            }
        }
    }
#pragma unroll
    for (int rf = 0; rf < RF; ++rf)
#pragma unroll
        for (int cf = 0; cf < CF; ++cf)
#pragma unroll
            for (int rr = 0; rr < 4; ++rr) {
                int gr = row0 + wm * (RF * 16) + rf * 16 + lg * 4 + rr;
                if (gr < M) {
                    int col = (wn * CF + cf) * 16 + lr;
                    Z[(size_t)gr * N + col] = f2b(acc[rf][cf][rr]);
                }
            }
}

template <int K, int N, bool FUSE, typename XT>
__global__ __launch_bounds__(256) void k_gemm(const XT* __restrict__ X,
                                              const u16* __restrict__ Wp,
                                              u16* __restrict__ Z,
                                              const float* __restrict__ bnA,
                                              const float* __restrict__ bnC, int M) {
    gemmM_body<K, N, FUSE, XT>(blockIdx.x, X, Wp, Z, bnA, bnC, M);
}

// fused: blocks [0, gemm_blocks) do GEMM1; the rest do the edge histogram
__global__ __launch_bounds__(256) void k_gemm1_hist(const float* __restrict__ X,
                                                    const u16* __restrict__ Wp,
                                                    u16* __restrict__ Z, int M,
                                                    int gemm_blocks,
                                                    const int* __restrict__ dst,
                                                    int* __restrict__ deg,
                                                    int* __restrict__ rank) {
    if ((int)blockIdx.x < gemm_blocks) {
        gemmM_body<DIN, HID, false, float>(blockIdx.x, X, Wp, Z, nullptr, nullptr, M);
    } else {
        int e = ((int)blockIdx.x - gemm_blocks) * 256 + (int)threadIdx.x;
        if (e < NE) rank[e] = atomicAdd(&deg[dst[e]], 1);
    }
}

// ---------------------------------------------------------------- aggregation, 96ch (bf16)
// One wave per node. dwordx4 gather geometry: row = 192 B = 12 lanes x 16 B.
//   lane = (r, j): r = lane>>4 in [0,4) = edge slot, j = lane&15 (j>=12 dup j=11).
//   One gather instruction fetches FOUR edge rows (4x fewer addresses through
//   the TA/L1 coalescer than dword/lane -- the round-3 measured win).
// Gathers use normal L2-allocating loads (nt was 1.9x slower, round 9).
// Epilogue: BN coefficient finalize fused via last-block ticket (replaces k_bncoef).
#define ACC8(UB, W)                                                     \
    acc[0] = fmaf(W, b2f((UB).x & 0xFFFFu), acc[0]);                    \
    acc[1] = fmaf(W, b2f((UB).x >> 16), acc[1]);                        \
    acc[2] = fmaf(W, b2f((UB).y & 0xFFFFu), acc[2]);                    \
    acc[3] = fmaf(W, b2f((UB).y >> 16), acc[3]);                        \
    acc[4] = fmaf(W, b2f((UB).z & 0xFFFFu), acc[4]);                    \
    acc[5] = fmaf(W, b2f((UB).z >> 16), acc[5]);                        \
    acc[6] = fmaf(W, b2f((UB).w & 0xFFFFu), acc[6]);                    \
    acc[7] = fmaf(W, b2f((UB).w >> 16), acc[7]);

__global__ __launch_bounds__(256) void k_agg96(const u16* __restrict__ Z,
                                               u16* __restrict__ H,
                                               const float* __restrict__ bias,
                                               const int* __restrict__ row_start,
                                               const u32* __restrict__ ewt,
                                               const float* __restrict__ dinv,
                                               float* __restrict__ gsum,
                                               float* __restrict__ gsq,
                                               const float* __restrict__ g,
                                               const float* __restrict__ be,
                                               float* __restrict__ bnA,
                                               float* __restrict__ bnC,
                                               int* __restrict__ cnt) {
    __shared__ float ssum[96], ssq[96];
    int tid = threadIdx.x;
    if (tid < 96) { ssum[tid] = 0.f; ssq[tid] = 0.f; }
    __syncthreads();
    int wid = tid >> 6, lane = tid & 63;
    int r = lane >> 4;                   // edge slot 0..3
    int jraw = lane & 15;
    int j = jraw < 12 ? jraw : 11;       // 16B slot within the 192B row
    bool jact = jraw < 12;
    u32 j16 = (u32)j << 4;
    const char* zb = (const char*)Z;     // row stride 192 B
    float bia[8];
#pragma unroll
    for (int k = 0; k < 8; ++k) bia[k] = bias[8 * j + k];
    float lsum[8], lsq[8];
#pragma unroll
    for (int k = 0; k < 8; ++k) { lsum[k] = 0.f; lsq[k] = 0.f; }
    const int S = gridDim.x * 4;

    int n = blockIdx.x * 4 + wid;
    int e0 = 0, e1 = 0;
    u32 pr = 0;
    if (n < NN) {
        e0 = row_start[n]; e1 = row_start[n + 1];
        if (e0 + lane < e1) pr = ewt[e0 + lane];
    }
    while (n < NN) {
        int n2 = n + S;
        int e0n = 0, e1n = 0;
        if (n2 < NN) { e0n = row_start[n2]; e1n = row_start[n2 + 1]; }
        u32 prn = 0;
        if (n2 < NN && e0n + lane < e1n) prn = ewt[e0n + lane];

        float dn = dinv[n];
        int m = e1 - e0;
        float acc[8];
        if (r == 0) {
            u32x4 us4 = ld16(zb + (u32)n * 192u + j16);
            acc[0] = dn * b2f(us4.x & 0xFFFFu); acc[1] = dn * b2f(us4.x >> 16);
            acc[2] = dn * b2f(us4.y & 0xFFFFu); acc[3] = dn * b2f(us4.y >> 16);
            acc[4] = dn * b2f(us4.z & 0xFFFFu); acc[5] = dn * b2f(us4.z >> 16);
            acc[6] = dn * b2f(us4.w & 0xFFFFu); acc[7] = dn * b2f(us4.w >> 16);
        } else {
#pragma unroll
            for (int k = 0; k < 8; ++k) acc[k] = 0.f;
        }

        if (m <= 16) {
            u32x4 ub[4]; float wc[4];
            int nch = (m + 3) >> 2;
#pragma unroll
            for (int c = 0; c < 4; ++c) {
                if (c < nch) {
                    int e = 4 * c + r;
                    u32 pk = __shfl(pr, e < m ? e : 0);
                    wc[c] = (e < m) ? edge_wt(pk) : 0.f;
                    ub[c] = ld16(zb + (pk >> 15) * 192u + j16);
                }
            }
#pragma unroll
            for (int c = 0; c < 4; ++c) {
                if (c < nch) { ACC8(ub[c], wc[c]); }
            }
        } else {
            // rare: deg > 16; windows of 64 edges, 4-edge chunks (latency exposed)
            for (int base = 0; base < m; base += 64) {
                u32 cw = pr;
                if (base) {
                    int idx = e0 + base + lane;
                    cw = (idx < e1) ? ewt[idx] : 0;
                }
                int lim = m - base; if (lim > 64) lim = 64;
                for (int c = 0; c < lim; c += 4) {
                    int e = c + r;
                    u32 pk = __shfl(cw, e < lim ? e : 0);
                    float w = (e < lim) ? edge_wt(pk) : 0.f;
                    u32x4 ub = ld16(zb + (pk >> 15) * 192u + j16);
                    ACC8(ub, w);
                }
            }
        }

        // combine across edge slots: lanes {l, l^16, l^32, l^48} share channels
#pragma unroll
        for (int k = 0; k < 8; ++k) {
            float v = acc[k];
            v += __shfl_xor(v, 16);
            v += __shfl_xor(v, 32);
            acc[k] = v;
        }
        if (r == 0 && jact) {
            float h[8];
#pragma unroll
            for (int k = 0; k < 8; ++k) {
                h[k] = fmaf(dn, acc[k], bia[k]);
                lsum[k] += h[k];
                lsq[k] = fmaf(h[k], h[k], lsq[k]);
            }
            uint4 o;
            o.x = (u32)f2b(h[0]) | ((u32)f2b(h[1]) << 16);
            o.y = (u32)f2b(h[2]) | ((u32)f2b(h[3]) << 16);
            o.z = (u32)f2b(h[4]) | ((u32)f2b(h[5]) << 16);
            o.w = (u32)f2b(h[6]) | ((u32)f2b(h[7]) << 16);
            *(uint4*)((char*)H + (u32)n * 192u + j16) = o;
        }
        n = n2; e0 = e0n; e1 = e1n; pr = prn;
    }
    if (r == 0 && jact) {
#pragma unroll
        for (int k = 0; k < 8; ++k) {
            atomicAdd(&ssum[8 * j + k], lsum[k]);
            atomicAdd(&ssq[8 * j + k], lsq[k]);
        }
    }
    __syncthreads();
    if (tid < 96) { atomicAdd(&gsum[tid], ssum[tid]); atomicAdd(&gsq[tid], ssq[tid]); }
    __syncthreads();

    // ---- last-block BN-coefficient finalize (replaces k_bncoef launch)
    __shared__ int lastBlk;
    if (tid == 0) {
        __threadfence();
        lastBlk = (atomicAdd(cnt, 1) == (int)gridDim.x - 1);
    }
    __syncthreads();
    if (lastBlk && tid < 96) {
        float s = atomicAdd(&gsum[tid], 0.f);   // coherent read
        float q = atomicAdd(&gsq[tid], 0.f);
        float mean = s * (1.f / NN);
        float var = q * (1.f / NN) - mean * mean;
        float inv = rsqrtf(var + BN_EPS);
        float a = g[tid] * inv;
        bnA[tid] = a;
        bnC[tid] = fmaf(-a, mean, be[tid]);
    }
}

// ---------------------------------------------------------------- final agg + log_softmax
// 4 nodes per wave (16-lane groups). Full-window gather: all <=16 edges in flight.
__global__ __launch_bounds__(256) void k_agg32_lsm(const u16* __restrict__ Z,
                                                   float* __restrict__ Out,
                                                   const float* __restrict__ bias,
                                                   const int* __restrict__ row_start,
                                                   const u32* __restrict__ ewt,
                                                   const float* __restrict__ dinv) {
    int tid = threadIdx.x;
    int wid = tid >> 6, lane = tid & 63;
    int g = lane >> 4, sl = lane & 15;
    const u32* zu = (const u32*)Z;  // row stride 16 dwords
    float b0 = bias[2 * sl], b1 = bias[2 * sl + 1];
    int stride = gridDim.x * 16;
    for (int n0 = (blockIdx.x * 4 + wid) * 4; n0 < NN; n0 += stride) {
        int n = n0 + g;
        bool vn = n < NN;
        float dn = vn ? dinv[n] : 0.f;
        u32 uself = vn ? zu[(size_t)n * 16 + sl] : 0;
        float a0a = dn * b2f(uself & 0xFFFFu);
        float a1a = dn * b2f(uself >> 16);
        float a0b = 0.f, a1b = 0.f;
        int e0 = vn ? row_start[n] : 0, e1 = vn ? row_start[n + 1] : 0;
        for (int eb = e0; eb < e1; eb += 16) {
            int m = e1 - eb; if (m > 16) m = 16;
            int idx = eb + sl;
            u32 plv = (idx < e1) ? ewt[idx] : 0;
            u32 u_[16]; float w_[16];
#pragma unroll
            for (int q = 0; q < 16; ++q) {
                bool v = q < m;
                u32 pk = __shfl(plv, v ? q : 0, 16);
                w_[q] = v ? edge_wt(pk) : 0.f;
                u_[q] = zu[(size_t)edge_src(pk) * 16 + sl];
            }
#pragma unroll
            for (int q = 0; q < 16; q += 2) {
                a0a = fmaf(w_[q], b2f(u_[q] & 0xFFFFu), a0a);
                a1a = fmaf(w_[q], b2f(u_[q] >> 16), a1a);
                a0b = fmaf(w_[q + 1], b2f(u_[q + 1] & 0xFFFFu), a0b);
                a1b = fmaf(w_[q + 1], b2f(u_[q + 1] >> 16), a1b);
            }
        }
        float v0 = fmaf(dn, a0a + a0b, b0);
        float v1 = fmaf(dn, a1a + a1b, b1);
        float mx = fmaxf(v0, v1);
#pragma unroll
        for (int off = 8; off; off >>= 1) mx = fmaxf(mx, __shfl_xor(mx, off, 16));
        float ex = __expf(v0 - mx) + __expf(v1 - mx);
#pragma unroll
        for (int off = 8; off; off >>= 1) ex += __shfl_xor(ex, off, 16);
        float lse = mx + __logf(ex);
        if (vn) {
            float2 o = make_float2(v0 - lse, v1 - lse);
            *(float2*)&Out[(size_t)n * 32 + 2 * sl] = o;
        }
    }
}

// ---------------------------------------------------------------- launch

extern "C" void kernel_launch(void* const* d_in, const int* in_sizes, int n_in,
                              void* d_out, int out_size, void* d_ws, size_t ws_size,
                              hipStream_t stream) {
    const float* x  = (const float*)d_in[0];
    const int* ei   = (const int*)d_in[1];   // [2, NE]: src then dst
    const float* W1 = (const float*)d_in[2];
    const float* b1 = (const float*)d_in[3];
    const float* W2 = (const float*)d_in[4];
    const float* b2 = (const float*)d_in[5];
    const float* W3 = (const float*)d_in[6];
    const float* b3 = (const float*)d_in[7];
    const float* g1 = (const float*)d_in[8];
    const float* be1 = (const float*)d_in[9];
    const float* g2 = (const float*)d_in[10];
    const float* be2 = (const float*)d_in[11];
    float* out = (float*)d_out;

    const int* src = ei;
    const int* dst = ei + NE;

    char* p = (char*)d_ws;
    size_t off = 0;
    auto take = [&](size_t bytes) {
        char* r = p + off;
        off = (off + bytes + 255) & ~(size_t)255;
        return r;
    };
    float* dinv      = (float*)take(NN * 4);
    int*   deg       = (int*)take(NN * 4);
    int*   row_start = (int*)take((NN + 1) * 4);
    int*   blksum    = (int*)take(SCAN_NB * 4);
    int*   rank      = (int*)take((size_t)NE * 4);
    u32*   ewt       = (u32*)take((size_t)NE * 4);
    float* meta      = (float*)take(772 * 4);
    u16*   w1p       = (u16*)take(24 * 512 * 2 * 2);   // hi+lo
    u16*   w2p       = (u16*)take(18 * 512 * 2 * 2);
    u16*   w3p       = (u16*)take(6 * 512 * 2 * 2);
    u16*   bufA      = (u16*)take((size_t)NN * HID * 2);
    u16*   bufB      = (u16*)take((size_t)NN * HID * 2);

    float* sum1 = meta + 0,   *sq1 = meta + 96;
    float* sum2 = meta + 192, *sq2 = meta + 288;
    float* bnA1 = meta + 384, *bnC1 = meta + 480;
    float* bnA2 = meta + 576, *bnC2 = meta + 672;
    int*   cnt1 = (int*)meta + 768;
    int*   cnt2 = (int*)meta + 769;

    const int EB = (NE + 255) / 256;   // 3125
    const int MB = (NN + 63) / 64;     // 1563 GEMM blocks
    const int AB = 2048;               // agg blocks: 8 per CU

    (void)hipMemsetAsync(deg, 0, NN * 4, stream);
    k_wpack<<<96, 256, 0, stream>>>(W1, W2, W3, w1p, w2p, w3p);
    // GEMM1 (independent of graph setup) fused with edge histogram
    k_gemm1_hist<<<MB + EB, 256, 0, stream>>>(x, w1p, bufA, NN, MB, dst, deg, rank);
    k_scan1<<<SCAN_NB, 256, 0, stream>>>(deg, row_start, blksum, dinv);
    k_scan2<<<1, 512, 0, stream>>>(blksum, row_start, meta);
    k_scan3<<<SCAN_NB, 256, 0, stream>>>(row_start, blksum);
    k_scatter<<<EB, 256, 0, stream>>>(src, dst, row_start, rank, dinv, ewt);

    // layer 1 aggregation (z1 already in bufA); BN coefs finalized in-kernel
    k_agg96<<<AB, 256, 0, stream>>>(bufA, bufB, b1, row_start, ewt, dinv,
                                    sum1, sq1, g1, be1, bnA1, bnC1, cnt1);

    // layer 2: z = relu(bn(h1))@W2 ; h2 = agg(z)+b2 (+stats)
    k_gemm<HID, HID, true, u16><<<MB, 256, 0, stream>>>(bufB, w2p, bufA, bnA1, bnC1, NN);
    k_agg96<<<AB, 256, 0, stream>>>(bufA, bufB, b2, row_start, ewt, dinv,
                                    sum2, sq2, g2, be2, bnA2, bnC2, cnt2);

    // layer 3: z = relu(bn(h2))@W3 ; out = log_softmax(agg(z)+b3)
    k_gemm<HID, DOUT, true, u16><<<MB, 256, 0, stream>>>(bufB, w3p, bufA, bnA2, bnC2, NN);
    k_agg32_lsm<<<AB, 256, 0, stream>>>(bufA, out, b3, row_start, ewt, dinv);

    (void)in_sizes; (void)n_in; (void)out_size; (void)ws_size;
}

// Round 11
// 383.878 us; speedup vs baseline: 1.3585x; 1.1609x over previous
//
#include <hip/hip_runtime.h>
#include <hip/hip_fp16.h>
#include <cstddef>

#define NN 100000
#define NE 800000
#define DIN 128
#define HID 96
#define DOUT 32
static constexpr float BN_EPS = 1e-5f;
#define SCAN_NB ((NN + 255) / 256)   // 391

typedef unsigned short u16;
typedef unsigned int u32;

using f32x4 = __attribute__((ext_vector_type(4))) float;
using bf16x8 = __attribute__((ext_vector_type(8))) short;

__device__ __forceinline__ float b2f(u32 lo16) {
    union { u32 u; float f; } c; c.u = lo16 << 16; return c.f;
}
__device__ __forceinline__ u16 f2b(float f) {
    union { float f; u32 u; } c; c.f = f;
    return (u16)((c.u + 0x7FFFu + ((c.u >> 16) & 1u)) >> 16);
}
// packed edge: bits[31:15] = src (17b), bits[14:0] = fp16 weight (sign bit 0, w>0)
__device__ __forceinline__ u32 pack_edge(int s, float w) {
    __half h = __float2half(w);
    return ((u32)s << 15) | (u32)__half_as_ushort(h);
}
__device__ __forceinline__ int edge_src(u32 pk) { return (int)(pk >> 15); }
__device__ __forceinline__ float edge_wt(u32 pk) {
    return __half2float(__ushort_as_half((u16)(pk & 0x7FFFu)));
}

// ---------------------------------------------------------------- setup kernels

// Pack W1/W2/W3 into MFMA B-fragment order, bf16 hi/lo split.
// Fragment f = kt*CFT + c; within: lane holds B[k = kt*32 + (lane>>4)*8 + j][col = c*16 + (lane&15)],
// flat u16 index f*512 + lane*8 + j. Lo plane at +nfrag*512.
__global__ __launch_bounds__(256) void k_wpack(const float* __restrict__ W1,
                                               const float* __restrict__ W2,
                                               const float* __restrict__ W3,
                                               u16* __restrict__ w1p,
                                               u16* __restrict__ w2p,
                                               u16* __restrict__ w3p) {
    int e = blockIdx.x * 256 + threadIdx.x;   // < 24576
    const float* W; u16* P; int N, nf, idx;
    if (e < 12288)      { W = W1; P = w1p; N = 96; nf = 24; idx = e; }
    else if (e < 21504) { W = W2; P = w2p; N = 96; nf = 18; idx = e - 12288; }
    else                { W = W3; P = w3p; N = 32; nf = 6;  idx = e - 21504; }
    int f = idx >> 9, r = idx & 511;
    int lane = r >> 3, j = r & 7;
    int CFT = N / 16;
    int kt = f / CFT, c = f % CFT;
    int k = kt * 32 + (lane >> 4) * 8 + j;
    int col = c * 16 + (lane & 15);
    float v = W[k * N + col];
    u16 hi = f2b(v);
    u16 lo = f2b(v - b2f(hi));
    P[idx] = hi;
    P[nf * 512 + idx] = lo;
}

// scan phase 1 + dinv fused
__global__ __launch_bounds__(256) void k_scan1(const int* __restrict__ deg,
                                               int* __restrict__ row_start,
                                               int* __restrict__ blksum,
                                               float* __restrict__ dinv) {
    __shared__ int lds[256];
    int t = threadIdx.x;
    int i = blockIdx.x * 256 + t;
    int v = (i < NN) ? deg[i] : 0;
    if (i < NN) dinv[i] = rsqrtf((float)(v + 1));  // +1 self-loop
    lds[t] = v;
    __syncthreads();
#pragma unroll
    for (int off = 1; off < 256; off <<= 1) {
        int add = (t >= off) ? lds[t - off] : 0;
        __syncthreads();
        lds[t] += add;
        __syncthreads();
    }
    if (i < NN) row_start[i] = lds[t] - v;  // exclusive
    if (t == 255) blksum[blockIdx.x] = lds[255];
}

// scans block sums; also zeroes BN-stat accumulators (needed before first agg96)
__global__ __launch_bounds__(512) void k_scan2(int* __restrict__ blksum,
                                               int* __restrict__ row_start,
                                               float* __restrict__ meta) {
    __shared__ int lds[512];
    int t = threadIdx.x;
    if (t < 384) meta[t] = 0.f;
    int v = (t < SCAN_NB) ? blksum[t] : 0;
    lds[t] = v;
    __syncthreads();
#pragma unroll
    for (int off = 1; off < 512; off <<= 1) {
        int add = (t >= off) ? lds[t - off] : 0;
        __syncthreads();
        lds[t] += add;
        __syncthreads();
    }
    if (t < SCAN_NB) blksum[t] = lds[t] - v;  // exclusive block offset
    if (t == 511) row_start[NN] = lds[511];   // grand total (= NE)
}

__global__ __launch_bounds__(256) void k_scan3(int* __restrict__ row_start,
                                               const int* __restrict__ blksum) {
    int i = blockIdx.x * 256 + threadIdx.x;
    if (i < NN) row_start[i] += blksum[blockIdx.x];
}

// atomic-free scatter: position = row_start[dst] + rank; 4 B packed payload
__global__ void k_scatter(const int* __restrict__ src, const int* __restrict__ dst,
                          const int* __restrict__ row_start,
                          const int* __restrict__ rank,
                          const float* __restrict__ dinv,
                          u32* __restrict__ ewt) {
    int e = blockIdx.x * blockDim.x + threadIdx.x;
    if (e < NE) {
        int d = dst[e];
        int p = row_start[d] + rank[e];
        int s = src[e];
        ewt[p] = pack_edge(s, dinv[s]);
    }
}

// ---------------------------------------------------------------- GEMM (bf16 MFMA, hi/lo split)
// Z[M x N](bf16) = f(X)[M x K] @ W[K x N], f = optional relu(a*x+c) per K-channel.
// 3-pass bf16 split (Ah*Bh + Al*Bh + Ah*Bl) keeps ~fp32 precision.
// Block = 64 rows x N cols; full-K A tile staged in LDS once (hi/lo), single barrier.
// B fragments come pre-packed from global (k_wpack), L2-hot, no LDS.
template <int K, int N, bool FUSE, typename XT>
__device__ __forceinline__ void gemmM_body(int bid, const XT* __restrict__ X,
                                           const u16* __restrict__ Wp,
                                           u16* __restrict__ Z,
                                           const float* __restrict__ bnA,
                                           const float* __restrict__ bnC, int M) {
    constexpr int KT = K / 32;          // 4 or 3
    constexpr int CFT = N / 16;         // 6 or 2
    constexpr int WN = (N == 96) ? 2 : 1;
    constexpr int WM = 4 / WN;          // 2 or 4
    constexpr int CF = CFT / WN;        // 3 or 2
    constexpr int RF = 64 / (WM * 16);  // 2 or 1
    constexpr int XSB = K + 8;          // LDS row stride (bf16), 16B-aligned
    __shared__ u16 Ah[64 * XSB];
    __shared__ u16 Al[64 * XSB];
    __shared__ float As[FUSE ? K : 1], Cs[FUSE ? K : 1];

    int tid = threadIdx.x;
    if (FUSE) {
        if (tid < K) { As[tid] = bnA[tid]; Cs[tid] = bnC[tid]; }
        __syncthreads();
    }
    int row0 = bid * 64;
    int sr = tid >> 2, sq = tid & 3;
    int grow = row0 + sr;
    if constexpr (sizeof(XT) == 4) {
        // fp32 X, K=128: 8 float4/thread, cols sq*32 + i*4
#pragma unroll
        for (int i = 0; i < 8; ++i) {
            int c0 = sq * 32 + i * 4;
            float4 v = make_float4(0.f, 0.f, 0.f, 0.f);
            if (grow < M) v = *(const float4*)&X[(size_t)grow * K + c0];
            float vv[4] = {v.x, v.y, v.z, v.w};
            u32 hpk[2], lpk[2];
#pragma unroll
            for (int p = 0; p < 2; ++p) {
                u16 h0 = f2b(vv[2 * p]), h1 = f2b(vv[2 * p + 1]);
                u16 l0 = f2b(vv[2 * p] - b2f(h0));
                u16 l1 = f2b(vv[2 * p + 1] - b2f(h1));
                hpk[p] = (u32)h0 | ((u32)h1 << 16);
                lpk[p] = (u32)l0 | ((u32)l1 << 16);
            }
            *(uint2*)&Ah[sr * XSB + c0] = make_uint2(hpk[0], hpk[1]);
            *(uint2*)&Al[sr * XSB + c0] = make_uint2(lpk[0], lpk[1]);
        }
    } else {
        // bf16 X, K=96: 3 uint4/thread, cols sq*24 + i*8; BN+ReLU fused in fp32
#pragma unroll
        for (int i = 0; i < 3; ++i) {
            int c0 = sq * 24 + i * 8;
            uint4 v = make_uint4(0, 0, 0, 0);
            if (grow < M) v = *(const uint4*)&X[(size_t)grow * K + c0];
            u32 w[4] = {v.x, v.y, v.z, v.w};
            u32 hq[4], lq[4];
#pragma unroll
            for (int p = 0; p < 4; ++p) {
                float x0 = b2f(w[p] & 0xFFFFu);
                float x1 = b2f(w[p] >> 16);
                if (FUSE) {
                    x0 = fmaxf(fmaf(As[c0 + 2 * p], x0, Cs[c0 + 2 * p]), 0.f);
                    x1 = fmaxf(fmaf(As[c0 + 2 * p + 1], x1, Cs[c0 + 2 * p + 1]), 0.f);
                }
                u16 h0 = f2b(x0), h1 = f2b(x1);
                u16 l0 = f2b(x0 - b2f(h0)), l1 = f2b(x1 - b2f(h1));
                hq[p] = (u32)h0 | ((u32)h1 << 16);
                lq[p] = (u32)l0 | ((u32)l1 << 16);
            }
            *(uint4*)&Ah[sr * XSB + c0] = make_uint4(hq[0], hq[1], hq[2], hq[3]);
            *(uint4*)&Al[sr * XSB + c0] = make_uint4(lq[0], lq[1], lq[2], lq[3]);
        }
    }
    __syncthreads();

    int wid = tid >> 6, lane = tid & 63;
    int wm = wid & (WM - 1), wn = wid / WM;
    int lr = lane & 15, lg = lane >> 4;
    f32x4 acc[RF][CF];
#pragma unroll
    for (int a = 0; a < RF; ++a)
#pragma unroll
        for (int b = 0; b < CF; ++b) acc[a][b] = (f32x4){0.f, 0.f, 0.f, 0.f};

    const u16* WpLo = Wp + KT * CFT * 512;
#pragma unroll
    for (int kt = 0; kt < KT; ++kt) {
        bf16x8 ah[RF], al[RF];
#pragma unroll
        for (int rf = 0; rf < RF; ++rf) {
            int row = wm * (RF * 16) + rf * 16 + lr;
            ah[rf] = *(const bf16x8*)&Ah[row * XSB + kt * 32 + lg * 8];
            al[rf] = *(const bf16x8*)&Al[row * XSB + kt * 32 + lg * 8];
        }
#pragma unroll
        for (int cf = 0; cf < CF; ++cf) {
            int f = kt * CFT + wn * CF + cf;
            bf16x8 bh = *(const bf16x8*)&Wp[f * 512 + lane * 8];
            bf16x8 bl = *(const bf16x8*)&WpLo[f * 512 + lane * 8];
#pragma unroll
            for (int rf = 0; rf < RF; ++rf) {
                acc[rf][cf] = __builtin_amdgcn_mfma_f32_16x16x32_bf16(ah[rf], bh, acc[rf][cf], 0, 0, 0);
                acc[rf][cf] = __builtin_amdgcn_mfma_f32_16x16x32_bf16(al[rf], bh, acc[rf][cf], 0, 0, 0);
                acc[rf][cf] = __builtin_amdgcn_mfma_f32_16x16x32_bf16(ah[rf], bl, acc[rf][cf], 0, 0, 0);
            }
        }
    }
#pragma unroll
    for (int rf = 0; rf < RF; ++rf)
#pragma unroll
        for (int cf = 0; cf < CF; ++cf)
#pragma unroll
            for (int rr = 0; rr < 4; ++rr) {
                int gr = row0 + wm * (RF * 16) + rf * 16 + lg * 4 + rr;
                if (gr < M) {
                    int col = (wn * CF + cf) * 16 + lr;
                    Z[(size_t)gr * N + col] = f2b(acc[rf][cf][rr]);
                }
            }
}

template <int K, int N, bool FUSE, typename XT>
__global__ __launch_bounds__(256) void k_gemm(const XT* __restrict__ X,
                                              const u16* __restrict__ Wp,
                                              u16* __restrict__ Z,
                                              const float* __restrict__ bnA,
                                              const float* __restrict__ bnC, int M) {
    gemmM_body<K, N, FUSE, XT>(blockIdx.x, X, Wp, Z, bnA, bnC, M);
}

// fused: blocks [0, gemm_blocks) do GEMM1; the rest do the edge histogram
__global__ __launch_bounds__(256) void k_gemm1_hist(const float* __restrict__ X,
                                                    const u16* __restrict__ Wp,
                                                    u16* __restrict__ Z, int M,
                                                    int gemm_blocks,
                                                    const int* __restrict__ dst,
                                                    int* __restrict__ deg,
                                                    int* __restrict__ rank) {
    if ((int)blockIdx.x < gemm_blocks) {
        gemmM_body<DIN, HID, false, float>(blockIdx.x, X, Wp, Z, nullptr, nullptr, M);
    } else {
        int e = ((int)blockIdx.x - gemm_blocks) * 256 + (int)threadIdx.x;
        if (e < NE) rank[e] = atomicAdd(&deg[dst[e]], 1);
    }
}

// ---------------------------------------------------------------- aggregation, 96ch (bf16)
// One wave per node. dwordx4 gather geometry: row = 192 B = 12 lanes x 16 B.
//   lane = (r, j): r = lane>>4 in [0,4) = edge slot, j = lane&15 (j>=12 dup j=11).
//   One gather instruction fetches FOUR edge rows (4x fewer addresses through the
//   TA/L1 coalescer than the dword/lane layout -- the measured wall).
// Each lane accumulates 8 channels (j*8..j*8+7) over edge subset e % 4 == r;
// cross-slot combine = shfl_xor 16/32 at node end. Self row loaded by r==0 group.
// ewt window for next node prefetched during compute.
// NOTE (r9/r10 A/B): plain L2-allocating loads; nt-loads were 1.9x slower, and
// fusing the BN finalize (device fence) into this kernel cost +33 us. Keep both out.
#define ACC8(UB, W)                                                     \
    acc[0] = fmaf(W, b2f((UB).x & 0xFFFFu), acc[0]);                    \
    acc[1] = fmaf(W, b2f((UB).x >> 16), acc[1]);                        \
    acc[2] = fmaf(W, b2f((UB).y & 0xFFFFu), acc[2]);                    \
    acc[3] = fmaf(W, b2f((UB).y >> 16), acc[3]);                        \
    acc[4] = fmaf(W, b2f((UB).z & 0xFFFFu), acc[4]);                    \
    acc[5] = fmaf(W, b2f((UB).z >> 16), acc[5]);                        \
    acc[6] = fmaf(W, b2f((UB).w & 0xFFFFu), acc[6]);                    \
    acc[7] = fmaf(W, b2f((UB).w >> 16), acc[7]);

__global__ __launch_bounds__(256) void k_agg96(const u16* __restrict__ Z,
                                               u16* __restrict__ H,
                                               const float* __restrict__ bias,
                                               const int* __restrict__ row_start,
                                               const u32* __restrict__ ewt,
                                               const float* __restrict__ dinv,
                                               float* __restrict__ gsum,
                                               float* __restrict__ gsq) {
    __shared__ float ssum[96], ssq[96];
    int tid = threadIdx.x;
    if (tid < 96) { ssum[tid] = 0.f; ssq[tid] = 0.f; }
    __syncthreads();
    int wid = tid >> 6, lane = tid & 63;
    int r = lane >> 4;                   // edge slot 0..3
    int jraw = lane & 15;
    int j = jraw < 12 ? jraw : 11;       // 16B slot within the 192B row
    bool jact = jraw < 12;
    u32 j16 = (u32)j << 4;
    const char* zb = (const char*)Z;     // row stride 192 B
    float bia[8];
#pragma unroll
    for (int k = 0; k < 8; ++k) bia[k] = bias[8 * j + k];
    float lsum[8], lsq[8];
#pragma unroll
    for (int k = 0; k < 8; ++k) { lsum[k] = 0.f; lsq[k] = 0.f; }
    const int S = gridDim.x * 4;

    int n = blockIdx.x * 4 + wid;
    int e0 = 0, e1 = 0;
    u32 pr = 0;
    if (n < NN) {
        e0 = row_start[n]; e1 = row_start[n + 1];
        if (e0 + lane < e1) pr = ewt[e0 + lane];
    }
    while (n < NN) {
        int n2 = n + S;
        int e0n = 0, e1n = 0;
        if (n2 < NN) { e0n = row_start[n2]; e1n = row_start[n2 + 1]; }
        u32 prn = 0;
        if (n2 < NN && e0n + lane < e1n) prn = ewt[e0n + lane];

        float dn = dinv[n];
        int m = e1 - e0;
        float acc[8];
        uint4 us4 = make_uint4(0, 0, 0, 0);
        if (r == 0) us4 = *(const uint4*)(zb + (u32)n * 192u + j16);
        if (r == 0) {
            acc[0] = dn * b2f(us4.x & 0xFFFFu); acc[1] = dn * b2f(us4.x >> 16);
            acc[2] = dn * b2f(us4.y & 0xFFFFu); acc[3] = dn * b2f(us4.y >> 16);
            acc[4] = dn * b2f(us4.z & 0xFFFFu); acc[5] = dn * b2f(us4.z >> 16);
            acc[6] = dn * b2f(us4.w & 0xFFFFu); acc[7] = dn * b2f(us4.w >> 16);
        } else {
#pragma unroll
            for (int k = 0; k < 8; ++k) acc[k] = 0.f;
        }

        if (m <= 16) {
            uint4 ub[4]; float wc[4];
            int nch = (m + 3) >> 2;
#pragma unroll
            for (int c = 0; c < 4; ++c) {
                if (c < nch) {
                    int e = 4 * c + r;
                    u32 pk = __shfl(pr, e < m ? e : 0);
                    wc[c] = (e < m) ? edge_wt(pk) : 0.f;
                    ub[c] = *(const uint4*)(zb + (pk >> 15) * 192u + j16);
                }
            }
#pragma unroll
            for (int c = 0; c < 4; ++c) {
                if (c < nch) { ACC8(ub[c], wc[c]); }
            }
        } else {
            // rare: deg > 16; windows of 64 edges, 4-edge chunks (latency exposed)
            for (int base = 0; base < m; base += 64) {
                u32 cw = pr;
                if (base) {
                    int idx = e0 + base + lane;
                    cw = (idx < e1) ? ewt[idx] : 0;
                }
                int lim = m - base; if (lim > 64) lim = 64;
                for (int c = 0; c < lim; c += 4) {
                    int e = c + r;
                    u32 pk = __shfl(cw, e < lim ? e : 0);
                    float w = (e < lim) ? edge_wt(pk) : 0.f;
                    uint4 ub = *(const uint4*)(zb + (pk >> 15) * 192u + j16);
                    ACC8(ub, w);
                }
            }
        }

        // combine across edge slots: lanes {l, l^16, l^32, l^48} share channels
#pragma unroll
        for (int k = 0; k < 8; ++k) {
            float v = acc[k];
            v += __shfl_xor(v, 16);
            v += __shfl_xor(v, 32);
            acc[k] = v;
        }
        if (r == 0 && jact) {
            float h[8];
#pragma unroll
            for (int k = 0; k < 8; ++k) {
                h[k] = fmaf(dn, acc[k], bia[k]);
                lsum[k] += h[k];
                lsq[k] = fmaf(h[k], h[k], lsq[k]);
            }
            uint4 o;
            o.x = (u32)f2b(h[0]) | ((u32)f2b(h[1]) << 16);
            o.y = (u32)f2b(h[2]) | ((u32)f2b(h[3]) << 16);
            o.z = (u32)f2b(h[4]) | ((u32)f2b(h[5]) << 16);
            o.w = (u32)f2b(h[6]) | ((u32)f2b(h[7]) << 16);
            *(uint4*)((char*)H + (u32)n * 192u + j16) = o;
        }
        n = n2; e0 = e0n; e1 = e1n; pr = prn;
    }
    if (r == 0 && jact) {
#pragma unroll
        for (int k = 0; k < 8; ++k) {
            atomicAdd(&ssum[8 * j + k], lsum[k]);
            atomicAdd(&ssq[8 * j + k], lsq[k]);
        }
    }
    __syncthreads();
    if (tid < 96) { atomicAdd(&gsum[tid], ssum[tid]); atomicAdd(&gsq[tid], ssq[tid]); }
}

__global__ void k_bncoef(const float* __restrict__ gsum, const float* __restrict__ gsq,
                         const float* __restrict__ g, const float* __restrict__ be,
                         float* __restrict__ bnA, float* __restrict__ bnC) {
    int c = threadIdx.x;
    if (c < 96) {
        float mean = gsum[c] * (1.f / NN);
        float var = gsq[c] * (1.f / NN) - mean * mean;
        float inv = rsqrtf(var + BN_EPS);
        float a = g[c] * inv;
        bnA[c] = a;
        bnC[c] = fmaf(-a, mean, be[c]);
    }
}

// ---------------------------------------------------------------- final agg + log_softmax
// 4 nodes per wave (16-lane groups). Full-window gather: all <=16 edges in flight.
__global__ __launch_bounds__(256) void k_agg32_lsm(const u16* __restrict__ Z,
                                                   float* __restrict__ Out,
                                                   const float* __restrict__ bias,
                                                   const int* __restrict__ row_start,
                                                   const u32* __restrict__ ewt,
                                                   const float* __restrict__ dinv) {
    int tid = threadIdx.x;
    int wid = tid >> 6, lane = tid & 63;
    int g = lane >> 4, sl = lane & 15;
    const u32* zu = (const u32*)Z;  // row stride 16 dwords
    float b0 = bias[2 * sl], b1 = bias[2 * sl + 1];
    int stride = gridDim.x * 16;
    for (int n0 = (blockIdx.x * 4 + wid) * 4; n0 < NN; n0 += stride) {
        int n = n0 + g;
        bool vn = n < NN;
        float dn = vn ? dinv[n] : 0.f;
        u32 uself = vn ? zu[(size_t)n * 16 + sl] : 0;
        float a0a = dn * b2f(uself & 0xFFFFu);
        float a1a = dn * b2f(uself >> 16);
        float a0b = 0.f, a1b = 0.f;
        int e0 = vn ? row_start[n] : 0, e1 = vn ? row_start[n + 1] : 0;
        for (int eb = e0; eb < e1; eb += 16) {
            int m = e1 - eb; if (m > 16) m = 16;
            int idx = eb + sl;
            u32 plv = (idx < e1) ? ewt[idx] : 0;
            u32 u_[16]; float w_[16];
#pragma unroll
            for (int q = 0; q < 16; ++q) {
                bool v = q < m;
                u32 pk = __shfl(plv, v ? q : 0, 16);
                w_[q] = v ? edge_wt(pk) : 0.f;
                u_[q] = zu[(size_t)edge_src(pk) * 16 + sl];
            }
#pragma unroll
            for (int q = 0; q < 16; q += 2) {
                a0a = fmaf(w_[q], b2f(u_[q] & 0xFFFFu), a0a);
                a1a = fmaf(w_[q], b2f(u_[q] >> 16), a1a);
                a0b = fmaf(w_[q + 1], b2f(u_[q + 1] & 0xFFFFu), a0b);
                a1b = fmaf(w_[q + 1], b2f(u_[q + 1] >> 16), a1b);
            }
        }
        float v0 = fmaf(dn, a0a + a0b, b0);
        float v1 = fmaf(dn, a1a + a1b, b1);
        float mx = fmaxf(v0, v1);
#pragma unroll
        for (int off = 8; off; off >>= 1) mx = fmaxf(mx, __shfl_xor(mx, off, 16));
        float ex = __expf(v0 - mx) + __expf(v1 - mx);
#pragma unroll
        for (int off = 8; off; off >>= 1) ex += __shfl_xor(ex, off, 16);
        float lse = mx + __logf(ex);
        if (vn) {
            float2 o = make_float2(v0 - lse, v1 - lse);
            *(float2*)&Out[(size_t)n * 32 + 2 * sl] = o;
        }
    }
}

// ---------------------------------------------------------------- launch

extern "C" void kernel_launch(void* const* d_in, const int* in_sizes, int n_in,
                              void* d_out, int out_size, void* d_ws, size_t ws_size,
                              hipStream_t stream) {
    const float* x  = (const float*)d_in[0];
    const int* ei   = (const int*)d_in[1];   // [2, NE]: src then dst
    const float* W1 = (const float*)d_in[2];
    const float* b1 = (const float*)d_in[3];
    const float* W2 = (const float*)d_in[4];
    const float* b2 = (const float*)d_in[5];
    const float* W3 = (const float*)d_in[6];
    const float* b3 = (const float*)d_in[7];
    const float* g1 = (const float*)d_in[8];
    const float* be1 = (const float*)d_in[9];
    const float* g2 = (const float*)d_in[10];
    const float* be2 = (const float*)d_in[11];
    float* out = (float*)d_out;

    const int* src = ei;
    const int* dst = ei + NE;

    char* p = (char*)d_ws;
    size_t off = 0;
    auto take = [&](size_t bytes) {
        char* r = p + off;
        off = (off + bytes + 255) & ~(size_t)255;
        return r;
    };
    float* dinv      = (float*)take(NN * 4);
    int*   deg       = (int*)take(NN * 4);
    int*   row_start = (int*)take((NN + 1) * 4);
    int*   blksum    = (int*)take(SCAN_NB * 4);
    int*   rank      = (int*)take((size_t)NE * 4);
    u32*   ewt       = (u32*)take((size_t)NE * 4);
    float* meta      = (float*)take(768 * 4);
    u16*   w1p       = (u16*)take(24 * 512 * 2 * 2);   // hi+lo
    u16*   w2p       = (u16*)take(18 * 512 * 2 * 2);
    u16*   w3p       = (u16*)take(6 * 512 * 2 * 2);
    u16*   bufA      = (u16*)take((size_t)NN * HID * 2);
    u16*   bufB      = (u16*)take((size_t)NN * HID * 2);

    float* sum1 = meta + 0,   *sq1 = meta + 96;
    float* sum2 = meta + 192, *sq2 = meta + 288;
    float* bnA1 = meta + 384, *bnC1 = meta + 480;
    float* bnA2 = meta + 576, *bnC2 = meta + 672;

    const int EB = (NE + 255) / 256;   // 3125
    const int MB = (NN + 63) / 64;     // 1563 GEMM blocks
    const int AB = 2048;               // agg blocks: 8 per CU

    (void)hipMemsetAsync(deg, 0, NN * 4, stream);
    k_wpack<<<96, 256, 0, stream>>>(W1, W2, W3, w1p, w2p, w3p);
    // GEMM1 (independent of graph setup) fused with edge histogram
    k_gemm1_hist<<<MB + EB, 256, 0, stream>>>(x, w1p, bufA, NN, MB, dst, deg, rank);
    k_scan1<<<SCAN_NB, 256, 0, stream>>>(deg, row_start, blksum, dinv);
    k_scan2<<<1, 512, 0, stream>>>(blksum, row_start, meta);
    k_scan3<<<SCAN_NB, 256, 0, stream>>>(row_start, blksum);
    k_scatter<<<EB, 256, 0, stream>>>(src, dst, row_start, rank, dinv, ewt);

    // layer 1 aggregation (z1 already in bufA)
    k_agg96<<<AB, 256, 0, stream>>>(bufA, bufB, b1, row_start, ewt, dinv, sum1, sq1);
    k_bncoef<<<1, 128, 0, stream>>>(sum1, sq1, g1, be1, bnA1, bnC1);

    // layer 2: z = relu(bn(h1))@W2 ; h2 = agg(z)+b2 (+stats)
    k_gemm<HID, HID, true, u16><<<MB, 256, 0, stream>>>(bufB, w2p, bufA, bnA1, bnC1, NN);
    k_agg96<<<AB, 256, 0, stream>>>(bufA, bufB, b2, row_start, ewt, dinv, sum2, sq2);
    k_bncoef<<<1, 128, 0, stream>>>(sum2, sq2, g2, be2, bnA2, bnC2);

    // layer 3: z = relu(bn(h2))@W3 ; out = log_softmax(agg(z)+b3)
    k_gemm<HID, DOUT, true, u16><<<MB, 256, 0, stream>>>(bufB, w3p, bufA, bnA2, bnC2, NN);
    k_agg32_lsm<<<AB, 256, 0, stream>>>(bufA, out, b3, row_start, ewt, dinv);

    (void)in_sizes; (void)n_in; (void)out_size; (void)ws_size;
}